// Round 3
// baseline (2237.479 us; speedup 1.0000x reference)
//
#include <hip/hip_runtime.h>
#include <hip/hip_bf16.h>
#include <stdint.h>

// B=16, N=4096, C=768, H=8, D=96
// cvt -> qk gemm (swapped-operand MFMA -> coalesced transposed qT,kT) + v gemm (token-major)
//   -> split-K qk^T gemm -> reduce+softmax (wave/row) -> attn@v -> proj gemm
typedef __bf16 bf16;
typedef __bf16 bf16x8 __attribute__((ext_vector_type(8)));
typedef __bf16 bf16x4 __attribute__((ext_vector_type(4)));
typedef float f32x4 __attribute__((ext_vector_type(4)));

__device__ __forceinline__ void gl_lds16(const bf16* g, bf16* l) {
  __builtin_amdgcn_global_load_lds(
      (const __attribute__((address_space(1))) void*)g,
      (__attribute__((address_space(3))) void*)l, 16, 0, 0);
}

__global__ void cvt_f32_bf16(const float* __restrict__ in, bf16* __restrict__ out, int n4) {
  int i = blockIdx.x * blockDim.x + threadIdx.x;
  if (i < n4) {
    float4 v = ((const float4*)in)[i];
    bf16x4 o;
    o[0] = (bf16)v.x; o[1] = (bf16)v.y; o[2] = (bf16)v.z; o[3] = (bf16)v.w;
    ((bf16x4*)out)[i] = o;
  }
}

// C = A @ B^T + bias.
// EPI=0: qk — swapped-operand MFMA gives D[ch][tok]; coalesced transposed write to qT/kT (q scaled)
// EPI=1: proj — fp32 out row-major
// EPI=2: v — bf16 out row-major (token-major V)
template<int EPI>
__global__ __launch_bounds__(256, 6) void gemm_bt(
    const bf16* __restrict__ A, const bf16* __restrict__ B,
    const float* __restrict__ bias, void* __restrict__ C0, void* __restrict__ C1,
    int M, int N, int K, int nbn)
{
  __shared__ __align__(16) bf16 sA[128 * 32];
  __shared__ __align__(16) bf16 sB[128 * 32];
  // XCD-contiguous tile swizzle (keeps per-XCD L2 on a contiguous row-block span)
  int tiles = gridDim.x;
  int bid = blockIdx.x;
  int tile = ((bid & 7) * (tiles >> 3)) + (bid >> 3);
  int bm = tile / nbn, bn = tile % nbn;
  int m0 = bm * 128, n0 = bn * 128;
  int t = threadIdx.x;
  int wave = t >> 6, lane = t & 63;
  int wm = wave >> 1, wn = wave & 1;
  int l16 = lane & 15, quad = lane >> 4;

  f32x4 acc[4][4] = {};

  int rA = (wave * 2) * 16 + (lane >> 2);
  int kk = (lane & 3) * 8;
  const bf16* gA = A + (long)(m0 + rA) * K + kk;
  const bf16* gB = B + (long)(n0 + rA) * K + kk;

  for (int k0 = 0; k0 < K; k0 += 32) {
    gl_lds16(gA + k0,          &sA[(wave * 2) * 512]);
    gl_lds16(gA + 16 * K + k0, &sA[(wave * 2 + 1) * 512]);
    gl_lds16(gB + k0,          &sB[(wave * 2) * 512]);
    gl_lds16(gB + 16 * K + k0, &sB[(wave * 2 + 1) * 512]);
    __syncthreads();
    bf16x8 af[4], bfr[4];
#pragma unroll
    for (int mi = 0; mi < 4; mi++)
      af[mi] = *(const bf16x8*)&sA[(wm * 64 + mi * 16 + l16) * 32 + quad * 8];
#pragma unroll
    for (int ni = 0; ni < 4; ni++)
      bfr[ni] = *(const bf16x8*)&sB[(wn * 64 + ni * 16 + l16) * 32 + quad * 8];
#pragma unroll
    for (int mi = 0; mi < 4; mi++)
#pragma unroll
      for (int ni = 0; ni < 4; ni++) {
        if (EPI == 0)  // swapped: D[ch][tok]
          acc[mi][ni] = __builtin_amdgcn_mfma_f32_16x16x32_bf16(bfr[ni], af[mi], acc[mi][ni], 0, 0, 0);
        else
          acc[mi][ni] = __builtin_amdgcn_mfma_f32_16x16x32_bf16(af[mi], bfr[ni], acc[mi][ni], 0, 0, 0);
      }
    __syncthreads();
  }

  if (EPI == 0) {
    // tile rows = channels (quad*4+r), tile cols = tokens (l16) -> coalesced 32B bursts
    bf16* T;
    int coff;
    float scale;
    if (n0 < 768) { T = (bf16*)C0; coff = 0;   scale = 0.015625f; }  // q * N^-0.5
    else          { T = (bf16*)C1; coff = 768; scale = 1.0f; }
    int b = m0 >> 12, tokB = m0 & 4095;
#pragma unroll
    for (int ni = 0; ni < 4; ni++) {
      int ch = n0 + wn * 64 + ni * 16 + quad * 4;
      float4 bv = *(const float4*)&bias[ch];
#pragma unroll
      for (int mi = 0; mi < 4; mi++) {
        int tok = tokB + wm * 64 + mi * 16 + l16;
        long base = ((long)(b * 768 + ch - coff)) * 4096 + tok;
        T[base]         = (bf16)((acc[mi][ni][0] + bv.x) * scale);
        T[base + 4096]  = (bf16)((acc[mi][ni][1] + bv.y) * scale);
        T[base + 8192]  = (bf16)((acc[mi][ni][2] + bv.z) * scale);
        T[base + 12288] = (bf16)((acc[mi][ni][3] + bv.w) * scale);
      }
    }
  } else {
#pragma unroll
    for (int mi = 0; mi < 4; mi++) {
      int row = m0 + wm * 64 + mi * 16 + quad * 4;
#pragma unroll
      for (int ni = 0; ni < 4; ni++) {
        int col = n0 + wn * 64 + ni * 16 + l16;
        float bv = bias[col];
#pragma unroll
        for (int r = 0; r < 4; r++) {
          float v = acc[mi][ni][r] + bv;
          if (EPI == 1) ((float*)C0)[(long)(row + r) * N + col] = v;
          else          ((bf16*)C0)[(long)(row + r) * N + col] = (bf16)v;
        }
      }
    }
  }
}

// part[(bh*8+s)][d][e] = sum_{n in chunk s} qT[b,h*96+d,n] * kT[b,h*96+e,n]
// BK=64 staging: full 128B-line global reads; XOR swizzle on k-chunk kills LDS read conflicts
__global__ __launch_bounds__(256) void attn_qk(
    const bf16* __restrict__ qT, const bf16* __restrict__ kT, float* __restrict__ part)
{
  __shared__ __align__(16) bf16 sQ[96 * 64];
  __shared__ __align__(16) bf16 sK[96 * 64];
  int bid = blockIdx.x;
  int bh = bid >> 3, s = bid & 3 | ((bid >> 2) & 1) << 2;  // s = bid & 7
  s = bid & 7;
  int b = bh >> 3, h = bh & 7;
  int t = threadIdx.x;
  int wave = t >> 6, lane = t & 63;
  int wm = wave >> 1, wn = wave & 1;
  int l16 = lane & 15, quad = lane >> 4;
  f32x4 acc[3][3] = {};
  const bf16* Qb = qT + ((long)(b * 768 + h * 96)) * 4096 + s * 512;
  const bf16* Kb = kT + ((long)(b * 768 + h * 96)) * 4096 + s * 512;

  int rsub = lane >> 3;                       // row within 8-row chunk
  int ksw = ((lane & 7) ^ (lane >> 3)) * 8;   // swizzled global k-offset

  for (int it = 0; it < 8; it++) {
#pragma unroll
    for (int j = 0; j < 6; j++) {
      int c2 = wave * 6 + j;                  // 0..23 (wave-uniform)
      int c = (c2 < 12) ? c2 : c2 - 12;
      const bf16* src = ((c2 < 12) ? Qb : Kb) + (long)(c * 8 + rsub) * 4096 + it * 64 + ksw;
      bf16* dst = ((c2 < 12) ? sQ : sK) + c * 512;
      gl_lds16(src, dst);
    }
    __syncthreads();
#pragma unroll
    for (int ks = 0; ks < 2; ks++) {
      bf16x8 af[3], bfr[3];
#pragma unroll
      for (int mi = 0; mi < 3; mi++) {
        int R = wm * 48 + mi * 16 + l16;
        af[mi] = *(const bf16x8*)&sQ[R * 64 + (((ks * 4 + quad) ^ (l16 & 7)) * 8)];
      }
#pragma unroll
      for (int ni = 0; ni < 3; ni++) {
        int R = wn * 48 + ni * 16 + l16;
        bfr[ni] = *(const bf16x8*)&sK[R * 64 + (((ks * 4 + quad) ^ (l16 & 7)) * 8)];
      }
#pragma unroll
      for (int mi = 0; mi < 3; mi++)
#pragma unroll
        for (int ni = 0; ni < 3; ni++)
          acc[mi][ni] = __builtin_amdgcn_mfma_f32_16x16x32_bf16(af[mi], bfr[ni], acc[mi][ni], 0, 0, 0);
    }
    __syncthreads();
  }
  float* pout = part + (long)bid * 9216;
#pragma unroll
  for (int mi = 0; mi < 3; mi++)
#pragma unroll
    for (int ni = 0; ni < 3; ni++) {
      int row = wm * 48 + mi * 16 + quad * 4;
      int col = wn * 48 + ni * 16 + l16;
#pragma unroll
      for (int r = 0; r < 4; r++)
        pout[(row + r) * 96 + col] = acc[mi][ni][r];
    }
}

// wave-per-row: sum 8 partials, softmax over 96, cast bf16. 12288 rows -> 3072 blocks
__global__ __launch_bounds__(256) void softmax_attn(const float* __restrict__ part, bf16* __restrict__ attn)
{
  int row = blockIdx.x * 4 + (threadIdx.x >> 6);
  int lane = threadIdx.x & 63;
  int bh = row / 96, d = row - bh * 96;
  const float* p = part + (long)bh * 8 * 9216 + d * 96;
  float va = 0.f, vb = 0.f;
#pragma unroll
  for (int k = 0; k < 8; k++) {
    va += p[k * 9216 + lane];
    if (lane < 32) vb += p[k * 9216 + 64 + lane];
  }
  float m = (lane < 32) ? fmaxf(va, vb) : va;
#pragma unroll
  for (int sft = 32; sft; sft >>= 1) m = fmaxf(m, __shfl_xor(m, sft));
  float ea = __expf(va - m);
  float eb = (lane < 32) ? __expf(vb - m) : 0.f;
  float s2 = ea + eb;
#pragma unroll
  for (int sft = 32; sft; sft >>= 1) s2 += __shfl_xor(s2, sft);
  float inv = 1.f / s2;
  bf16* ao = attn + (long)bh * 9216 + d * 96;
  ao[lane] = (bf16)(ea * inv);
  if (lane < 32) ao[64 + lane] = (bf16)(eb * inv);
}

// out2[tok, h*96+d] = sum_e V[tok,e] * attn[d,e]
__global__ __launch_bounds__(256) void attn_v(
    const bf16* __restrict__ V, const bf16* __restrict__ attn, bf16* __restrict__ out2)
{
  __shared__ __align__(16) bf16 sV[128 * 96];
  __shared__ __align__(16) bf16 sAt[96 * 96];
  int bh = blockIdx.x >> 5, tb = blockIdx.x & 31;
  int b = bh >> 3, h = bh & 7;
  int tok0 = tb * 128;
  int t = threadIdx.x;
  int wave = t >> 6, lane = t & 63;
  int wm = wave >> 1, wn = wave & 1;
  int l16 = lane & 15, quad = lane >> 4;
  f32x4 acc[4][3] = {};
  const bf16* Vb = V + (long)b * 4096 * 768 + h * 96;

#pragma unroll
  for (int j = 0; j < 6; j++) {
    int c = wave * 6 + j;
    int g = c * 64 + lane;
    int tok = g / 12, cc = g % 12;
    gl_lds16(Vb + (long)(tok0 + tok) * 768 + cc * 8, &sV[c * 512]);
  }
  for (int c = wave; c < 18; c += 4) {
    int g = c * 64 + lane;
    int d = g / 12, cc = g % 12;
    gl_lds16(attn + (long)bh * 9216 + d * 96 + cc * 8, &sAt[c * 512]);
  }
  __syncthreads();
#pragma unroll
  for (int ks = 0; ks < 3; ks++) {
    bf16x8 af[4], bfr[3];
#pragma unroll
    for (int mi = 0; mi < 4; mi++)
      af[mi] = *(const bf16x8*)&sV[(wm * 64 + mi * 16 + l16) * 96 + ks * 32 + quad * 8];
#pragma unroll
    for (int ni = 0; ni < 3; ni++)
      bfr[ni] = *(const bf16x8*)&sAt[(wn * 48 + ni * 16 + l16) * 96 + ks * 32 + quad * 8];
#pragma unroll
    for (int mi = 0; mi < 4; mi++)
#pragma unroll
      for (int ni = 0; ni < 3; ni++)
        acc[mi][ni] = __builtin_amdgcn_mfma_f32_16x16x32_bf16(af[mi], bfr[ni], acc[mi][ni], 0, 0, 0);
  }
  bf16* ob = out2 + (long)(b * 4096 + tok0) * 768 + h * 96;
#pragma unroll
  for (int mi = 0; mi < 4; mi++)
#pragma unroll
    for (int ni = 0; ni < 3; ni++) {
      int row = wm * 64 + mi * 16 + quad * 4;
      int col = wn * 48 + ni * 16 + l16;
#pragma unroll
      for (int r = 0; r < 4; r++)
        ob[(long)(row + r) * 768 + col] = (bf16)acc[mi][ni][r];
    }
}

extern "C" void kernel_launch(void* const* d_in, const int* in_sizes, int n_in,
                              void* d_out, int out_size, void* d_ws, size_t ws_size,
                              hipStream_t stream) {
  const float* x      = (const float*)d_in[0];
  const float* w_qkv  = (const float*)d_in[1];
  const float* b_qkv  = (const float*)d_in[2];
  const float* w_proj = (const float*)d_in[3];
  const float* b_proj = (const float*)d_in[4];

  char* ws = (char*)d_ws;
  // Region R (100,663,296 B) time-shared: Xb -> part -> out2 (strictly sequential consumers)
  bf16*  Xb     = (bf16*)ws;
  float* part   = (float*)ws;                     // 37,748,736 B
  bf16*  out2   = (bf16*)ws;
  bf16*  Wqkvb  = (bf16*)(ws + 100663296);        //   3,538,944 B
  bf16*  Wprojb = (bf16*)(ws + 104202240);        //   1,179,648 B
  bf16*  qT     = (bf16*)(ws + 105381888);        // 100,663,296 B
  bf16*  kT     = (bf16*)(ws + 206045184);        // 100,663,296 B
  bf16*  Vbuf   = (bf16*)(ws + 306708480);        // 100,663,296 B
  bf16*  attnb  = (bf16*)(ws + 407371776);        //   2,359,296 B

  cvt_f32_bf16<<<(12582912 + 255) / 256, 256, 0, stream>>>(x, Xb, 12582912);
  cvt_f32_bf16<<<(442368 + 255) / 256, 256, 0, stream>>>(w_qkv, Wqkvb, 442368);
  cvt_f32_bf16<<<(147456 + 255) / 256, 256, 0, stream>>>(w_proj, Wprojb, 147456);

  // q,k = x @ w_qkv[0:1536]^T + b  -> transposed qT,kT (q scaled by N^-0.5)
  gemm_bt<0><<<512 * 12, 256, 0, stream>>>(Xb, Wqkvb, b_qkv, qT, kT, 65536, 4096, 768, 12);
  // v = x @ w_qkv[1536:2304]^T + b -> token-major Vbuf
  gemm_bt<2><<<512 * 6, 256, 0, stream>>>(Xb, Wqkvb + 1536 * 768, b_qkv + 1536, Vbuf, nullptr, 65536, 768, 768, 6);
  // attn partials, split-K=8 over tokens
  attn_qk<<<1024, 256, 0, stream>>>(qT, kT, part);
  softmax_attn<<<3072, 256, 0, stream>>>(part, attnb);
  // out2 = (attn @ v^T)^T merged heads -> [65536, 768] bf16
  attn_v<<<4096, 256, 0, stream>>>(Vbuf, attnb, out2);
  // final: out2 @ w_proj^T + b -> fp32 d_out
  gemm_bt<1><<<512 * 6, 256, 0, stream>>>(out2, Wprojb, b_proj, d_out, nullptr, 65536, 768, 768, 6);
}